// Round 14
// baseline (1765.134 us; speedup 1.0000x reference)
//
#include <hip/hip_runtime.h>
#include <hip/hip_bf16.h>

// ---------------------------------------------------------------------------
// SurpriseKimiDeltaAttention  (B=2, T=4096, H=2048, NH=16, DK=DV=128, CONV=4)
// R14 = R13 chunked scan; phaseb stages KW/QW/KV in LDS as raw bf16
// (half the LDS traffic; decode on consume).  Lane l16 owns dims l16*8..+7.
// ---------------------------------------------------------------------------

typedef __attribute__((ext_vector_type(8))) short bf16x8;
typedef __attribute__((ext_vector_type(4))) float floatx4;

#define TB 4096
#define RSH 664                      // shorts per record
#define NREC 4096
#define BHSH ((size_t)NREC * RSH)    // shorts per (b,h) stream
#define CSB ((size_t)16 * RSH * 2)   // chunk span bytes = 21248

__device__ __forceinline__ float b2f(ushort u) {
    union { unsigned int u; float f; } c; c.u = ((unsigned int)u) << 16; return c.f;
}
__device__ __forceinline__ ushort f2b(float f) {
    union { float f; unsigned int u; } c; c.f = f;
    unsigned int r = (c.u + 0x7fffu + ((c.u >> 16) & 1u)) >> 16;
    return (ushort)r;
}
__device__ __forceinline__ float silu(float x) { return x / (1.0f + expf(-x)); }
__device__ __forceinline__ void dec8(uint4 u, float* f) {
    f[0] = __uint_as_float(u.x << 16); f[1] = __uint_as_float(u.x & 0xffff0000u);
    f[2] = __uint_as_float(u.y << 16); f[3] = __uint_as_float(u.y & 0xffff0000u);
    f[4] = __uint_as_float(u.z << 16); f[5] = __uint_as_float(u.z & 0xffff0000u);
    f[6] = __uint_as_float(u.w << 16); f[7] = __uint_as_float(u.w & 0xffff0000u);
}

// ---------------------------------------------------------------------------
__global__ __launch_bounds__(256) void cast_f32_bf16(const float* __restrict__ in,
                                                     ushort* __restrict__ out, int n) {
    int i = (blockIdx.x * 256 + threadIdx.x) * 4;
    int stride = gridDim.x * 256 * 4;
    for (; i + 3 < n; i += stride) {
        float4 v = *(const float4*)(in + i);
        ushort4 u;
        u.x = f2b(v.x); u.y = f2b(v.y); u.z = f2b(v.z); u.w = f2b(v.w);
        *(ushort4*)(out + i) = u;
    }
}

// ---------------------------------------------------------------------------
// bf16 MFMA GEMM: C[M][N] = A[M][K] @ B[N][K]^T  (row-major, K contiguous)
// ---------------------------------------------------------------------------
template <typename CT>
__global__ __launch_bounds__(256) void gemm_bf16(const ushort* __restrict__ A,
                                                 const ushort* __restrict__ B,
                                                 CT* __restrict__ C, int M, int N, int K) {
    __shared__ ushort As[128 * 40];
    __shared__ ushort Bs[128 * 40];
    const int tid = threadIdx.x;
    const int lane = tid & 63, wid = tid >> 6;
    const int wr = wid >> 1, wc = wid & 1;
    const int bm = blockIdx.y, bn = blockIdx.x;

    const int r0 = tid >> 2;
    const int kc0 = (tid & 3) * 8;
    const size_t aoff0 = (size_t)(bm * 128 + r0) * K + kc0;
    const size_t aoff1 = aoff0 + (size_t)64 * K;
    const size_t boff0 = (size_t)(bn * 128 + r0) * K + kc0;
    const size_t boff1 = boff0 + (size_t)64 * K;
    const int lw0 = r0 * 40 + kc0;
    const int lw1 = (r0 + 64) * 40 + kc0;

    const int arow = wr * 64 + (lane & 15);
    const int brow = wc * 64 + (lane & 15);
    const int kg = (lane >> 4) * 8;

    floatx4 acc[4][4];
#pragma unroll
    for (int m = 0; m < 4; ++m)
#pragma unroll
        for (int n = 0; n < 4; ++n) acc[m][n] = (floatx4){0.f, 0.f, 0.f, 0.f};

    uint4 ra0 = *(const uint4*)(A + aoff0);
    uint4 ra1 = *(const uint4*)(A + aoff1);
    uint4 rb0 = *(const uint4*)(B + boff0);
    uint4 rb1 = *(const uint4*)(B + boff1);

    for (int kt = 32; kt <= K; kt += 32) {
        __syncthreads();
        *(uint4*)(As + lw0) = ra0;
        *(uint4*)(As + lw1) = ra1;
        *(uint4*)(Bs + lw0) = rb0;
        *(uint4*)(Bs + lw1) = rb1;
        __syncthreads();
        if (kt < K) {
            ra0 = *(const uint4*)(A + aoff0 + kt);
            ra1 = *(const uint4*)(A + aoff1 + kt);
            rb0 = *(const uint4*)(B + boff0 + kt);
            rb1 = *(const uint4*)(B + boff1 + kt);
        }
        bf16x8 af[4], bfr[4];
#pragma unroll
        for (int m = 0; m < 4; ++m) af[m] = *(const bf16x8*)(As + (arow + m * 16) * 40 + kg);
#pragma unroll
        for (int n = 0; n < 4; ++n) bfr[n] = *(const bf16x8*)(Bs + (brow + n * 16) * 40 + kg);
#pragma unroll
        for (int m = 0; m < 4; ++m)
#pragma unroll
            for (int n = 0; n < 4; ++n)
                acc[m][n] = __builtin_amdgcn_mfma_f32_16x16x32_bf16(af[m], bfr[n], acc[m][n], 0, 0, 0);
    }

    const int crow0 = bm * 128 + wr * 64 + (lane >> 4) * 4;
    const int ccol0 = bn * 128 + wc * 64 + (lane & 15);
#pragma unroll
    for (int m = 0; m < 4; ++m)
#pragma unroll
        for (int n = 0; n < 4; ++n)
#pragma unroll
            for (int j = 0; j < 4; ++j) {
                int row = crow0 + m * 16 + j;
                int col = ccol0 + n * 16;
                if constexpr (sizeof(CT) == 2)
                    C[(size_t)row * N + col] = (CT)f2b(acc[m][n][j]);
                else
                    C[(size_t)row * N + col] = (CT)acc[m][n][j];
            }
}

// ---------------------------------------------------------------------------
// conv + silu + surprise stats + beta/amp MLPs -> records (one batch)
// lane owns dims (2*lane, 2*lane+1); record: q~@128 k@256 E@384 v@512 beta@640
// ---------------------------------------------------------------------------
__global__ __launch_bounds__(256) void conv_stats_kernel(
    const ushort* __restrict__ qkv,
    const float* __restrict__ convq, const float* __restrict__ convk,
    const float* __restrict__ convv, const float* __restrict__ Wsv,
    const float* __restrict__ Wb1, const float* __restrict__ bb1,
    const float* __restrict__ Wb2, const float* __restrict__ bb2,
    const float* __restrict__ Wa1, const float* __restrict__ ba1,
    const float* __restrict__ Wa2, const float* __restrict__ ba2,
    const float* __restrict__ A_log, const float* __restrict__ dt_bias,
    ushort* __restrict__ P) {
    __shared__ ushort wsv_s[128 * 136];
    __shared__ float k_sh[4][128];
    for (int i = threadIdx.x; i < 128 * 128; i += 256) {
        int row = i >> 7, col = i & 127;
        wsv_s[row * 136 + col] = f2b(Wsv[i]);
    }
    __syncthreads();
    const int wid = threadIdx.x >> 6, lane = threadIdx.x & 63;

    for (int it = 0; it < 2; ++it) {
        const int pair = blockIdx.x * 8 + it * 4 + wid;   // [0, TB*16)
        const int t = pair >> 4, h = pair & 15;
        const int c0 = h * 128 + 2 * lane, c1 = c0 + 1;

        float wq[4], wq2[4], wk[4], wk2[4], wv[4], wv2[4];
#pragma unroll
        for (int i2 = 0; i2 < 4; ++i2) {
            wq[i2] = convq[c0 * 4 + i2]; wq2[i2] = convq[c1 * 4 + i2];
            wk[i2] = convk[c0 * 4 + i2]; wk2[i2] = convk[c1 * 4 + i2];
            wv[i2] = convv[c0 * 4 + i2]; wv2[i2] = convv[c1 * 4 + i2];
        }
        float aq0 = 0, aq1 = 0, ak0 = 0, ak1 = 0, av0 = 0, av1 = 0;
#pragma unroll
        for (int i2 = 0; i2 < 4; ++i2) {
            int tt = t - 3 + i2;
            if (tt >= 0) {
                const ushort* rowp = qkv + (size_t)tt * 6144 + h * 128;
                uint xq = *(const uint*)(rowp + 2 * lane);
                uint xk = *(const uint*)(rowp + 2048 + 2 * lane);
                uint xv = *(const uint*)(rowp + 4096 + 2 * lane);
                aq0 = fmaf(__uint_as_float(xq << 16), wq[i2], aq0);
                aq1 = fmaf(__uint_as_float(xq & 0xffff0000u), wq2[i2], aq1);
                ak0 = fmaf(__uint_as_float(xk << 16), wk[i2], ak0);
                ak1 = fmaf(__uint_as_float(xk & 0xffff0000u), wk2[i2], ak1);
                av0 = fmaf(__uint_as_float(xv << 16), wv[i2], av0);
                av1 = fmaf(__uint_as_float(xv & 0xffff0000u), wv2[i2], av1);
            }
        }
        float q0 = silu(aq0), q1 = silu(aq1);
        float k0 = silu(ak0), k1 = silu(ak1);
        float v0 = silu(av0), v1 = silu(av1);

        __syncthreads();
        k_sh[wid][2 * lane] = k0;
        k_sh[wid][2 * lane + 1] = k1;
        __syncthreads();

        float vh0 = 0.f, vh1 = 0.f;
        const ushort* wr0 = wsv_s + (2 * lane) * 136;
        const ushort* wr1 = wsv_s + (2 * lane + 1) * 136;
#pragma unroll 4
        for (int j = 0; j < 128; j += 8) {
            float4 ka = *(const float4*)&k_sh[wid][j];
            float4 kb = *(const float4*)&k_sh[wid][j + 4];
            uint4 wa = *(const uint4*)(wr0 + j);
            uint4 wb = *(const uint4*)(wr1 + j);
            vh0 = fmaf(__uint_as_float(wa.x << 16), ka.x, vh0);
            vh0 = fmaf(__uint_as_float(wa.x & 0xffff0000u), ka.y, vh0);
            vh0 = fmaf(__uint_as_float(wa.y << 16), ka.z, vh0);
            vh0 = fmaf(__uint_as_float(wa.y & 0xffff0000u), ka.w, vh0);
            vh0 = fmaf(__uint_as_float(wa.z << 16), kb.x, vh0);
            vh0 = fmaf(__uint_as_float(wa.z & 0xffff0000u), kb.y, vh0);
            vh0 = fmaf(__uint_as_float(wa.w << 16), kb.z, vh0);
            vh0 = fmaf(__uint_as_float(wa.w & 0xffff0000u), kb.w, vh0);
            vh1 = fmaf(__uint_as_float(wb.x << 16), ka.x, vh1);
            vh1 = fmaf(__uint_as_float(wb.x & 0xffff0000u), ka.y, vh1);
            vh1 = fmaf(__uint_as_float(wb.y << 16), ka.z, vh1);
            vh1 = fmaf(__uint_as_float(wb.y & 0xffff0000u), ka.w, vh1);
            vh1 = fmaf(__uint_as_float(wb.z << 16), kb.x, vh1);
            vh1 = fmaf(__uint_as_float(wb.z & 0xffff0000u), kb.y, vh1);
            vh1 = fmaf(__uint_as_float(wb.w << 16), kb.z, vh1);
            vh1 = fmaf(__uint_as_float(wb.w & 0xffff0000u), kb.w, vh1);
        }

        float e0 = vh0 - v0, e1 = vh1 - v1;
        float se2 = e0 * e0 + e1 * e1;
        float sl1 = fabsf(e0) + fabsf(e1);
        float shv = vh0 * v0 + vh1 * v1;
        float shh = vh0 * vh0 + vh1 * vh1;
        float svv = v0 * v0 + v1 * v1;
        float sk2 = k0 * k0 + k1 * k1;
        float sq2 = q0 * q0 + q1 * q1;
#pragma unroll
        for (int m = 32; m >= 1; m >>= 1) {
            se2 += __shfl_xor(se2, m);
            sl1 += __shfl_xor(sl1, m);
            shv += __shfl_xor(shv, m);
            shh += __shfl_xor(shh, m);
            svv += __shfl_xor(svv, m);
            sk2 += __shfl_xor(sk2, m);
            sq2 += __shfl_xor(sq2, m);
        }
        float s_l2 = sqrtf(se2 + 1e-6f);
        float s_l1 = sl1;
        float s_cos = 1.0f - shv / (sqrtf(shh + 1e-6f) * sqrtf(svv + 1e-6f) + 1e-6f);

        const int j2 = lane & 31;
        const float* W1 = (lane < 32) ? Wb1 : Wa1;
        const float* b1 = (lane < 32) ? bb1 : ba1;
        const float* W2 = (lane < 32) ? Wb2 : Wa2;
        float pre = W1[j2 * 3] * s_l2 + W1[j2 * 3 + 1] * s_l1 + W1[j2 * 3 + 2] * s_cos + b1[j2];
        float val = W2[j2] * silu(pre);
#pragma unroll
        for (int m = 16; m >= 1; m >>= 1) val += __shfl_xor(val, m);
        float pre_b = __shfl(val, 0) + bb2[0];
        float pre_a = __shfl(val, 32) + ba2[0];
        float betav = 1.0f / (1.0f + expf(-pre_b));
        float amp = pre_a;

        float knorm = sqrtf(sk2);
        float rinv = amp / fmaxf(knorm, 1e-12f);
        float ah = expf(A_log[h]);
        float gr0 = fmaf(k0, rinv, dt_bias[c0]);
        float gr1 = fmaf(k1, rinv, dt_bias[c1]);
        float sp0 = (gr0 > 20.f) ? gr0 : log1pf(expf(gr0));
        float sp1 = (gr1 > 20.f) ? gr1 : log1pf(expf(gr1));

        ushort* rec = P + (size_t)h * BHSH + (size_t)t * RSH;
        float kinv = rsqrtf(sk2 + 1e-6f);
        float qinv = rsqrtf(sq2 + 1e-6f) * 0.08838834764831845f;  // * DK^-0.5
        *(uint*)(rec + 128 + 2 * lane) = (uint)f2b(q0 * qinv) | ((uint)f2b(q1 * qinv) << 16);
        *(uint*)(rec + 256 + 2 * lane) = (uint)f2b(k0 * kinv) | ((uint)f2b(k1 * kinv) << 16);
        *(uint*)(rec + 384 + 2 * lane) = (uint)f2b(expf(-ah * sp0)) | ((uint)f2b(expf(-ah * sp1)) << 16);
        *(uint*)(rec + 512 + 2 * lane) = (uint)f2b(v0) | ((uint)f2b(v1) << 16);
        if (lane == 0) *(float*)(rec + 640) = betav;
    }
}

// ---------------------------------------------------------------------------
// phase A: one wave per (stream, chunk).  In-place chunk-block construction.
// ---------------------------------------------------------------------------
__global__ __launch_bounds__(256, 1) void phasea_kernel(ushort* __restrict__ P) {
    __shared__ float lA[4][16][16];
    __shared__ float lU[4][16][16];
    __shared__ float lM[4][16][16];
    const int wid = threadIdx.x >> 6, lane = threadIdx.x & 63;
    const int g = blockIdx.x * 4 + wid;
    const int s = g >> 8, n = g & 255;
    ushort* cb = P + (size_t)s * BHSH + (size_t)n * (16 * RSH);
    char* sb = (char*)cb;
    float (*A_)[16] = lA[wid];
    float (*U_)[16] = lU[wid];
    float (*M_)[16] = lM[wid];

    float kf[32], Ef[32], qf[32], bf[16];
    uint vq[16];
#pragma unroll
    for (int i = 0; i < 16; ++i) {
        const ushort* r = cb + i * RSH;
        uint ku = *(const uint*)(r + 256 + 2 * lane);
        uint eu = *(const uint*)(r + 384 + 2 * lane);
        uint qu = *(const uint*)(r + 128 + 2 * lane);
        vq[i] = *(const uint*)(r + 512 + 2 * lane);
        bf[i] = *(const float*)(r + 640);
        kf[2 * i]     = __uint_as_float(ku << 16);
        kf[2 * i + 1] = __uint_as_float(ku & 0xffff0000u);
        Ef[2 * i]     = __uint_as_float(eu << 16);
        Ef[2 * i + 1] = __uint_as_float(eu & 0xffff0000u);
        qf[2 * i]     = __uint_as_float(qu << 16);
        qf[2 * i + 1] = __uint_as_float(qu & 0xffff0000u);
    }

    float R[32];
    float Pc0 = 1.f, Pc1 = 1.f;
#pragma unroll
    for (int i = 0; i < 16; ++i) {
#pragma unroll
        for (int j = 0; j < 16; ++j) if (j < i) {
            R[2 * j] *= Ef[2 * i];
            R[2 * j + 1] *= Ef[2 * i + 1];
        }
        float Tr[16], Ur[16];
#pragma unroll
        for (int j = 0; j < 16; ++j) { Tr[j] = 0.f; Ur[j] = 0.f; }
#pragma unroll
        for (int j = 0; j < 16; ++j) if (j < i) {
            Tr[j] = kf[2 * i] * R[2 * j] + kf[2 * i + 1] * R[2 * j + 1];
            Ur[j] = qf[2 * i] * R[2 * j] + qf[2 * i + 1] * R[2 * j + 1];
        }
        Ur[i] = qf[2 * i] * kf[2 * i] + qf[2 * i + 1] * kf[2 * i + 1];
#pragma unroll
        for (int m = 1; m <= 32; m <<= 1) {
#pragma unroll
            for (int j = 0; j < 16; ++j) if (j <= i) {
                if (j < i) Tr[j] += __shfl_xor(Tr[j], m);
                Ur[j] += __shfl_xor(Ur[j], m);
            }
        }
        if (lane == 0) {
#pragma unroll
            for (int j = 0; j < 16; ++j) if (j < i) A_[i][j] = bf[i] * Tr[j];
#pragma unroll
            for (int j = 0; j < 16; ++j) if (j <= i) U_[i][j] = Ur[j];
        }
        R[2 * i] = kf[2 * i];
        R[2 * i + 1] = kf[2 * i + 1];
        Pc0 *= Ef[2 * i];
        Pc1 *= Ef[2 * i + 1];
        *(uint*)(sb + (size_t)i * 256 + 4 * lane) =
            (uint)f2b(kf[2 * i] * Pc0) | ((uint)f2b(kf[2 * i + 1] * Pc1) << 16);
        *(uint*)(sb + 4096 + (size_t)i * 256 + 4 * lane) =
            (uint)f2b(qf[2 * i] * Pc0) | ((uint)f2b(qf[2 * i + 1] * Pc1) << 16);
    }
    *(uint*)(sb + 16384 + 4 * lane) = (uint)f2b(Pc0) | ((uint)f2b(Pc1) << 16);
    {
        uint lw[8], hw[8];
#pragma unroll
        for (int w = 0; w < 8; ++w) {
            lw[w] = (vq[2 * w] & 0xffffu) | (vq[2 * w + 1] << 16);
            hw[w] = (vq[2 * w] >> 16) | (vq[2 * w + 1] & 0xffff0000u);
        }
        char* vt0 = sb + 12288 + (size_t)(2 * lane) * 32;
        *(uint4*)(vt0)      = (uint4){lw[0], lw[1], lw[2], lw[3]};
        *(uint4*)(vt0 + 16) = (uint4){lw[4], lw[5], lw[6], lw[7]};
        *(uint4*)(vt0 + 32) = (uint4){hw[0], hw[1], hw[2], hw[3]};
        *(uint4*)(vt0 + 48) = (uint4){hw[4], hw[5], hw[6], hw[7]};
    }
    const int mcol = lane & 15;
    float M[16];
#pragma unroll
    for (int i = 0; i < 16; ++i) {
        float acc = (i == mcol) ? bf[i] : 0.f;
#pragma unroll
        for (int j = 0; j < 16; ++j) if (j < i) acc -= A_[i][j] * M[j];
        M[i] = acc;
    }
    if (lane < 16) {
#pragma unroll
        for (int j = 0; j < 16; ++j) M_[j][lane] = M[j];
    }
    if (lane < 16) {
#pragma unroll
        for (int i = 0; i < 16; ++i) {
            float acc = 0.f;
#pragma unroll
            for (int j = 0; j < 16; ++j) if (j <= i) acc += U_[i][j] * M[j];
            *(float*)(sb + 16640 + (size_t)i * 64 + 4 * lane) = acc;
        }
    }
#pragma unroll
    for (int m = 0; m < 16; ++m) {
        float a0 = 0.f, a1 = 0.f;
#pragma unroll
        for (int j = 0; j < 16; ++j) if (j >= m) {
            float mv = M_[j][m];
            a0 = fmaf(mv, R[2 * j], a0);
            a1 = fmaf(mv, R[2 * j + 1], a1);
        }
        *(uint*)(sb + 8192 + (size_t)m * 256 + 4 * lane) =
            (uint)f2b(a0) | ((uint)f2b(a1) << 16);
    }
}

// ---------------------------------------------------------------------------
// owner-reduce: lane l16 (within 16-lane group) ends with full sum of Y[l16].
// ---------------------------------------------------------------------------
__device__ __forceinline__ float ownred16(const float* Y, int l16) {
    float a8[8], a4[4], a2[2];
    const bool b0 = (l16 & 1) != 0;
#pragma unroll
    for (int k = 0; k < 8; ++k) {
        float t  = b0 ? Y[2 * k] : Y[2 * k + 1];
        float kp = b0 ? Y[2 * k + 1] : Y[2 * k];
        a8[k] = kp + __shfl_xor(t, 1);
    }
    const bool b1 = (l16 & 2) != 0;
#pragma unroll
    for (int k = 0; k < 4; ++k) {
        float t  = b1 ? a8[2 * k] : a8[2 * k + 1];
        float kp = b1 ? a8[2 * k + 1] : a8[2 * k];
        a4[k] = kp + __shfl_xor(t, 2);
    }
    const bool b2 = (l16 & 4) != 0;
#pragma unroll
    for (int k = 0; k < 2; ++k) {
        float t  = b2 ? a4[2 * k] : a4[2 * k + 1];
        float kp = b2 ? a4[2 * k + 1] : a4[2 * k];
        a2[k] = kp + __shfl_xor(t, 4);
    }
    const bool b3 = (l16 & 8) != 0;
    float t  = b3 ? a2[0] : a2[1];
    float kp = b3 ? a2[1] : a2[0];
    return kp + __shfl_xor(t, 8);
}

// ---------------------------------------------------------------------------
// phase B: sequential over 256 chunks; block = (stream, 16-col slice).
// KW/QW/KV staged in LDS as raw bf16 (half traffic); lane l16 owns dims
// l16*8..+7 (one b128 per row per array; consecutive across lanes).
// ---------------------------------------------------------------------------
__global__ __launch_bounds__(256, 1) void phaseb_kernel(const ushort* __restrict__ P,
                                                        ushort* __restrict__ ob,
                                                        int smask, int sshift) {
    __shared__ ushort kwh[2][2048];
    __shared__ ushort qwh[2][2048];
    __shared__ ushort kvh[2][2048];
    const int tid = threadIdx.x;
    const int l16 = tid & 15, cg = tid >> 4;
    const int s = blockIdx.x & smask, c = blockIdx.x >> sshift;
    const int b = s >> 4, h = s & 15;
    const int col = c * 16 + cg;
    const char* gb = (const char*)(P + (size_t)s * BHSH);
    ushort* opb = ob + (size_t)b * (TB * 2048) + h * 128 + col;
    const int fo = tid * 8;             // shorts: thread stages 8 bf16 per array
    const int ro = l16 * 8;             // owned dims l16*8..+7 (shorts)
    const int gbase = tid & 48;         // 16-group base lane (within wave)

    auto stage = [&](int pb, uint4 sA, uint4 sB, uint4 sC) {
        *(uint4*)&kwh[pb][fo] = sA;
        *(uint4*)&qwh[pb][fo] = sB;
        *(uint4*)&kvh[pb][fo] = sC;
    };

    uint4 sA = *(const uint4*)(gb + (size_t)fo * 2);
    uint4 sB = *(const uint4*)(gb + 4096 + (size_t)fo * 2);
    uint4 sC = *(const uint4*)(gb + 8192 + (size_t)fo * 2);
    stage(0, sA, sB, sC);
    sA = *(const uint4*)(gb + CSB + (size_t)fo * 2);
    sB = *(const uint4*)(gb + CSB + 4096 + (size_t)fo * 2);
    sC = *(const uint4*)(gb + CSB + 8192 + (size_t)fo * 2);
    __syncthreads();

    float S[8];
#pragma unroll
    for (int i = 0; i < 8; ++i) S[i] = 0.f;
    int p = 0;

    for (int n = 0; n < 256; ++n) {
        const char* cbn = gb + (size_t)n * CSB;
        // per-chunk global loads (latency hidden under Y/Z dots)
        float vf_own = b2f(*(const ushort*)(cbn + 12288 + (size_t)col * 32 + l16 * 2));
        uint4 wu = *(const uint4*)(cbn + 16384 + (size_t)l16 * 16);   // W15 dims l16*8..+7
        float um[16];
        *(float4*)&um[0]  = *(const float4*)(cbn + 16640 + (size_t)l16 * 64);
        *(float4*)&um[4]  = *(const float4*)(cbn + 16640 + (size_t)l16 * 64 + 16);
        *(float4*)&um[8]  = *(const float4*)(cbn + 16640 + (size_t)l16 * 64 + 32);
        *(float4*)&um[12] = *(const float4*)(cbn + 16640 + (size_t)l16 * 64 + 48);
        // stage chunk n+1 into buffer p^1
        if (n < 255) stage(p ^ 1, sA, sB, sC);
        // prefetch chunk n+2
        if (n < 254) {
            const char* pf = gb + (size_t)(n + 2) * CSB;
            sA = *(const uint4*)(pf + (size_t)fo * 2);
            sB = *(const uint4*)(pf + 4096 + (size_t)fo * 2);
            sC = *(const uint4*)(pf + 8192 + (size_t)fo * 2);
        }
        // Y = KW.S0, Z = QW.S0  (partial over this lane's 8 dims; bf16 decode)
        float Y[16], Z[16];
#pragma unroll
        for (int i = 0; i < 16; ++i) {
            uint4 ku = *(const uint4*)&kwh[p][i * 128 + ro];
            uint4 qu = *(const uint4*)&qwh[p][i * 128 + ro];
            float kf[8], qf[8];
            dec8(ku, kf); dec8(qu, qf);
            Y[i] = kf[0] * S[0] + kf[1] * S[1] + kf[2] * S[2] + kf[3] * S[3]
                 + kf[4] * S[4] + kf[5] * S[5] + kf[6] * S[6] + kf[7] * S[7];
            Z[i] = qf[0] * S[0] + qf[1] * S[1] + qf[2] * S[2] + qf[3] * S[3]
                 + qf[4] * S[4] + qf[5] * S[5] + qf[6] * S[6] + qf[7] * S[7];
        }
        // owner-reduce (lane l16 gets full Y[l16], Z[l16])
        float Yo = ownred16(Y, l16);
        float Zo = ownred16(Z, l16);
        float rro = vf_own - Yo;
        // gather rr[0..15] to all lanes of the group
        float rrg[16];
#pragma unroll
        for (int j = 0; j < 16; ++j) rrg[j] = __shfl(rro, gbase + j);
        // S-update first (inter-chunk critical chain): S = W15*S + sum_m KV'_m rr_m
        {
            float wf[8];
            dec8(wu, wf);
#pragma unroll
            for (int d = 0; d < 8; ++d) S[d] *= wf[d];
        }
#pragma unroll
        for (int m2 = 0; m2 < 16; ++m2) {
            uint4 vu = *(const uint4*)&kvh[p][m2 * 128 + ro];
            float vf[8];
            dec8(vu, vf);
            S[0] = fmaf(vf[0], rrg[m2], S[0]);
            S[1] = fmaf(vf[1], rrg[m2], S[1]);
            S[2] = fmaf(vf[2], rrg[m2], S[2]);
            S[3] = fmaf(vf[3], rrg[m2], S[3]);
            S[4] = fmaf(vf[4], rrg[m2], S[4]);
            S[5] = fmaf(vf[5], rrg[m2], S[5]);
            S[6] = fmaf(vf[6], rrg[m2], S[6]);
            S[7] = fmaf(vf[7], rrg[m2], S[7]);
        }
        // o for row i = l16 (off critical chain)
        float oo = Zo;
#pragma unroll
        for (int j = 0; j < 16; ++j) oo = fmaf(um[j], rrg[j], oo);
        opb[(size_t)(n * 16 + l16) * 2048] = f2b(oo);
        __syncthreads();
        p ^= 1;
    }
}

// ---------------------------------------------------------------------------
// gated RMS norm: og = bf16( o*rsqrt(mean o^2+1e-5)*norm_w*sigmoid(gate+bg2) )
// ---------------------------------------------------------------------------
__global__ __launch_bounds__(256) void normgate_kernel(
    const ushort* __restrict__ o, const ushort* __restrict__ gate,
    const float* __restrict__ bg2, const float* __restrict__ norm_w,
    ushort* __restrict__ og) {
    const int lane = threadIdx.x & 63;
    const int wstart = (blockIdx.x * 256 + threadIdx.x) >> 6;
    const int nw = (gridDim.x * 256) >> 6;
    for (int pair = wstart; pair < TB * 16; pair += nw) {
        const int t = pair >> 4, h = pair & 15;
        const size_t basep = (size_t)t * 2048 + h * 128 + lane * 2;
        unsigned int ovu = *(const unsigned int*)(o + basep);
        float o0 = __uint_as_float(ovu << 16);
        float o1 = __uint_as_float(ovu & 0xffff0000u);
        float ss = o0 * o0 + o1 * o1;
#pragma unroll
        for (int m = 32; m >= 1; m >>= 1) ss += __shfl_xor(ss, m);
        float rn = rsqrtf(ss * (1.0f / 128.0f) + 1e-5f);
        const int dg = h * 128 + lane * 2;
        unsigned int gv = *(const unsigned int*)(gate + basep);
        float g0 = __uint_as_float(gv << 16) + bg2[dg];
        float g1 = __uint_as_float(gv & 0xffff0000u) + bg2[dg + 1];
        float w0 = norm_w[lane * 2], w1 = norm_w[lane * 2 + 1];
        float r0 = o0 * rn * w0 / (1.0f + expf(-g0));
        float r1 = o1 * rn * w1 / (1.0f + expf(-g1));
        unsigned int outw = (unsigned int)f2b(r0) | ((unsigned int)f2b(r1) << 16);
        *(unsigned int*)(og + basep) = outw;
    }
}

// ---------------------------------------------------------------------------
extern "C" void kernel_launch(void* const* d_in, const int* in_sizes, int n_in,
                              void* d_out, int out_size, void* d_ws, size_t ws_size,
                              hipStream_t stream) {
    const float* x = (const float*)d_in[0];
    const float* Wq = (const float*)d_in[1];
    const float* Wk = (const float*)d_in[2];
    const float* Wv = (const float*)d_in[3];
    const float* convq = (const float*)d_in[4];
    const float* convk = (const float*)d_in[5];
    const float* convv = (const float*)d_in[6];
    const float* A_log = (const float*)d_in[7];
    const float* dt_bias = (const float*)d_in[8];
    const float* Wsv = (const float*)d_in[9];
    const float* Wb1 = (const float*)d_in[10];
    const float* bb1 = (const float*)d_in[11];
    const float* Wb2 = (const float*)d_in[12];
    const float* bb2 = (const float*)d_in[13];
    const float* Wa1 = (const float*)d_in[14];
    const float* ba1 = (const float*)d_in[15];
    const float* Wa2 = (const float*)d_in[16];
    const float* ba2 = (const float*)d_in[17];
    const float* Wg1 = (const float*)d_in[18];
    const float* Wg2 = (const float*)d_in[19];
    const float* bg2 = (const float*)d_in[20];
    const float* norm_w = (const float*)d_in[21];
    const float* Wo = (const float*)d_in[22];

    // ---- workspace layout (bytes) ----
    const size_t PBATCH   = (size_t)16 * BHSH * 2;      // 87,031,808 per batch
    const size_t OFF_WQKV = 0;                          // 25,165,824
    const size_t OFF_XB   = OFF_WQKV + 25165824;        // 16,777,216
    const size_t OFF_WG1  = OFF_XB + 16777216;          //    524,288
    const size_t OFF_WG2  = OFF_WG1 + 524288;           //    524,288
    const size_t OFF_QKV  = OFF_WG2 + 524288;           // 50,331,648
    const size_t OFF_P    = OFF_QKV + 50331648;         // = 93,323,264
    const size_t NEED_B   = OFF_P + PBATCH;             // ~180.4 MB
    const size_t NEED_A   = OFF_P + 2 * PBATCH;         // ~267.4 MB
    if (ws_size < NEED_B) return;  // diagnostic guard
    const bool planA = (ws_size >= NEED_A);

    char* ws = (char*)d_ws;
    ushort* wqkv = (ushort*)(ws + OFF_WQKV);
    ushort* xb   = (ushort*)(ws + OFF_XB);
    ushort* wg1b = (ushort*)(ws + OFF_WG1);
    ushort* wg2b = (ushort*)(ws + OFF_WG2);
    ushort* qkvb = (ushort*)(ws + OFF_QKV);
    ushort* P    = (ushort*)(ws + OFF_P);
    ushort* gateb = qkvb;                               // +0        16,777,216
    ushort* xg1b  = (ushort*)(ws + OFF_QKV + 16777216); // +16.78M    1,048,576
    ushort* ogb   = (ushort*)(ws + OFF_QKV + 17825792); // +17.83M   16,777,216
    ushort* wob   = (ushort*)(ws + OFF_QKV + 34603008); // +34.60M    8,388,608
    ushort* obp = planA ? (ushort*)(ws + OFF_WQKV) : xb;

    // weight casts
    cast_f32_bf16<<<512, 256, 0, stream>>>(Wq, wqkv, 4194304);
    cast_f32_bf16<<<512, 256, 0, stream>>>(Wk, wqkv + 4194304, 4194304);
    cast_f32_bf16<<<512, 256, 0, stream>>>(Wv, wqkv + 8388608, 4194304);
    cast_f32_bf16<<<64, 256, 0, stream>>>(Wg1, wg1b, 262144);
    cast_f32_bf16<<<64, 256, 0, stream>>>(Wg2, wg2b, 262144);

    if (planA) {
        for (int b = 0; b < 2; ++b) {
            cast_f32_bf16<<<512, 256, 0, stream>>>(x + (size_t)b * TB * 2048, xb, TB * 2048);
            gemm_bf16<ushort><<<dim3(48, TB / 128), 256, 0, stream>>>(xb, wqkv, qkvb, TB, 6144, 2048);
            conv_stats_kernel<<<TB * 16 / 8, 256, 0, stream>>>(qkvb, convq, convk, convv, Wsv,
                Wb1, bb1, Wb2, bb2, Wa1, ba1, Wa2, ba2, A_log, dt_bias,
                P + (size_t)b * 16 * BHSH);
        }
        phasea_kernel<<<2048, 256, 0, stream>>>(P);
        phaseb_kernel<<<256, 256, 0, stream>>>(P, obp, 31, 5);
        cast_f32_bf16<<<512, 256, 0, stream>>>(Wo, wob, 4194304);
        for (int b = 0; b < 2; ++b) {
            ushort* xstage = ogb;
            cast_f32_bf16<<<512, 256, 0, stream>>>(x + (size_t)b * TB * 2048, xstage, TB * 2048);
            gemm_bf16<ushort><<<dim3(1, TB / 128), 256, 0, stream>>>(xstage, wg1b, xg1b, TB, 128, 2048);
            gemm_bf16<ushort><<<dim3(16, TB / 128), 256, 0, stream>>>(xg1b, wg2b, gateb, TB, 2048, 128);
            normgate_kernel<<<2048, 256, 0, stream>>>(obp + (size_t)b * TB * 2048, gateb, bg2, norm_w, ogb);
            gemm_bf16<float><<<dim3(16, TB / 128), 256, 0, stream>>>(ogb, wob,
                (float*)d_out + (size_t)b * TB * 2048, TB, 2048, 2048);
        }
    } else {
        for (int b = 0; b < 2; ++b) {
            const float* xbp = x + (size_t)b * TB * 2048;
            float* outp = (float*)d_out + (size_t)b * TB * 2048;
            cast_f32_bf16<<<512, 256, 0, stream>>>(xbp, xb, TB * 2048);
            gemm_bf16<ushort><<<dim3(48, TB / 128), 256, 0, stream>>>(xb, wqkv, qkvb, TB, 6144, 2048);
            conv_stats_kernel<<<TB * 16 / 8, 256, 0, stream>>>(qkvb, convq, convk, convv, Wsv,
                Wb1, bb1, Wb2, bb2, Wa1, ba1, Wa2, ba2, A_log, dt_bias, P);
            gemm_bf16<ushort><<<dim3(1, TB / 128), 256, 0, stream>>>(xb, wg1b, xg1b, TB, 128, 2048);
            gemm_bf16<ushort><<<dim3(16, TB / 128), 256, 0, stream>>>(xg1b, wg2b, gateb, TB, 2048, 128);
            cast_f32_bf16<<<512, 256, 0, stream>>>(Wo, wob, 4194304);
            phasea_kernel<<<1024, 256, 0, stream>>>(P);
            phaseb_kernel<<<128, 256, 0, stream>>>(P, xb, 15, 4);   // xb dead -> ob
            normgate_kernel<<<2048, 256, 0, stream>>>(xb, gateb, bg2, norm_w, ogb);
            gemm_bf16<float><<<dim3(16, TB / 128), 256, 0, stream>>>(ogb, wob, outp, TB, 2048, 2048);
        }
    }
}

// Round 15
// 1357.791 us; speedup vs baseline: 1.3000x; 1.3000x over previous
//
#include <hip/hip_runtime.h>
#include <hip/hip_bf16.h>

// ---------------------------------------------------------------------------
// SurpriseKimiDeltaAttention  (B=2, T=4096, H=2048, NH=16, DK=DV=128, CONV=4)
// R15 = chunked scan with MFMA phaseb.
// Chunk block (per stream, chunk n; within 16-record span, 21248 B):
//   KW bf16[16][128] @0 | QW @4096 | KVT bf16[128][16] @8192 |
//   vT bf16[128][16] @12288 | W15 bf16[128] @16384 | UM bf16[16][16] @16640
// phaseb per (stream, 16-col group), ONE wave:
//   Y/Z = KW/QW @ S (8x mfma_16x16x16_bf16, S held as 8 f32 D-tiles);
//   rr = v - Y;  o = mfma(UM, rr, Z);  S' = mfma(KVT_t, rr, W15*S_t).
//   B-operand k-layout == C/D row layout -> S re-enters mfma with f2b only.
// ---------------------------------------------------------------------------

typedef __attribute__((ext_vector_type(8))) short bf16x8;
typedef __attribute__((ext_vector_type(4))) short bf16x4;
typedef __attribute__((ext_vector_type(4))) float floatx4;

#define TB 4096
#define RSH 664                      // shorts per record
#define NREC 4096
#define BHSH ((size_t)NREC * RSH)    // shorts per (b,h) stream
#define CSB ((size_t)16 * RSH * 2)   // chunk span bytes = 21248

__device__ __forceinline__ float b2f(ushort u) {
    union { unsigned int u; float f; } c; c.u = ((unsigned int)u) << 16; return c.f;
}
__device__ __forceinline__ ushort f2b(float f) {
    union { float f; unsigned int u; } c; c.f = f;
    unsigned int r = (c.u + 0x7fffu + ((c.u >> 16) & 1u)) >> 16;
    return (ushort)r;
}
__device__ __forceinline__ float silu(float x) { return x / (1.0f + expf(-x)); }
__device__ __forceinline__ void dec8(uint4 u, float* f) {
    f[0] = __uint_as_float(u.x << 16); f[1] = __uint_as_float(u.x & 0xffff0000u);
    f[2] = __uint_as_float(u.y << 16); f[3] = __uint_as_float(u.y & 0xffff0000u);
    f[4] = __uint_as_float(u.z << 16); f[5] = __uint_as_float(u.z & 0xffff0000u);
    f[6] = __uint_as_float(u.w << 16); f[7] = __uint_as_float(u.w & 0xffff0000u);
}
__device__ __forceinline__ void dec4(uint2 u, float* f) {
    f[0] = __uint_as_float(u.x << 16); f[1] = __uint_as_float(u.x & 0xffff0000u);
    f[2] = __uint_as_float(u.y << 16); f[3] = __uint_as_float(u.y & 0xffff0000u);
}
__device__ __forceinline__ bf16x4 asbf(uint2 u) {
    union { uint2 a; bf16x4 b; } c; c.a = u; return c.b;
}

#if __has_builtin(__builtin_amdgcn_mfma_f32_16x16x16bf16_1k)
__device__ __forceinline__ floatx4 MFMA16(bf16x4 a, bf16x4 b, floatx4 c) {
    return __builtin_amdgcn_mfma_f32_16x16x16bf16_1k(a, b, c, 0, 0, 0);
}
#else
__device__ __forceinline__ floatx4 MFMA16(bf16x4 a, bf16x4 b, floatx4 c) {
    asm volatile("v_mfma_f32_16x16x16_bf16 %0, %1, %2, %0\n\ts_nop 7\n\ts_nop 7"
                 : "+v"(c) : "v"(a), "v"(b));
    return c;
}
#endif

// ---------------------------------------------------------------------------
__global__ __launch_bounds__(256) void cast_f32_bf16(const float* __restrict__ in,
                                                     ushort* __restrict__ out, int n) {
    int i = (blockIdx.x * 256 + threadIdx.x) * 4;
    int stride = gridDim.x * 256 * 4;
    for (; i + 3 < n; i += stride) {
        float4 v = *(const float4*)(in + i);
        ushort4 u;
        u.x = f2b(v.x); u.y = f2b(v.y); u.z = f2b(v.z); u.w = f2b(v.w);
        *(ushort4*)(out + i) = u;
    }
}

// ---------------------------------------------------------------------------
// bf16 MFMA GEMM: C[M][N] = A[M][K] @ B[N][K]^T  (row-major, K contiguous)
// ---------------------------------------------------------------------------
template <typename CT>
__global__ __launch_bounds__(256) void gemm_bf16(const ushort* __restrict__ A,
                                                 const ushort* __restrict__ B,
                                                 CT* __restrict__ C, int M, int N, int K) {
    __shared__ ushort As[128 * 40];
    __shared__ ushort Bs[128 * 40];
    const int tid = threadIdx.x;
    const int lane = tid & 63, wid = tid >> 6;
    const int wr = wid >> 1, wc = wid & 1;
    const int bm = blockIdx.y, bn = blockIdx.x;

    const int r0 = tid >> 2;
    const int kc0 = (tid & 3) * 8;
    const size_t aoff0 = (size_t)(bm * 128 + r0) * K + kc0;
    const size_t aoff1 = aoff0 + (size_t)64 * K;
    const size_t boff0 = (size_t)(bn * 128 + r0) * K + kc0;
    const size_t boff1 = boff0 + (size_t)64 * K;
    const int lw0 = r0 * 40 + kc0;
    const int lw1 = (r0 + 64) * 40 + kc0;

    const int arow = wr * 64 + (lane & 15);
    const int brow = wc * 64 + (lane & 15);
    const int kg = (lane >> 4) * 8;

    floatx4 acc[4][4];
#pragma unroll
    for (int m = 0; m < 4; ++m)
#pragma unroll
        for (int n = 0; n < 4; ++n) acc[m][n] = (floatx4){0.f, 0.f, 0.f, 0.f};

    uint4 ra0 = *(const uint4*)(A + aoff0);
    uint4 ra1 = *(const uint4*)(A + aoff1);
    uint4 rb0 = *(const uint4*)(B + boff0);
    uint4 rb1 = *(const uint4*)(B + boff1);

    for (int kt = 32; kt <= K; kt += 32) {
        __syncthreads();
        *(uint4*)(As + lw0) = ra0;
        *(uint4*)(As + lw1) = ra1;
        *(uint4*)(Bs + lw0) = rb0;
        *(uint4*)(Bs + lw1) = rb1;
        __syncthreads();
        if (kt < K) {
            ra0 = *(const uint4*)(A + aoff0 + kt);
            ra1 = *(const uint4*)(A + aoff1 + kt);
            rb0 = *(const uint4*)(B + boff0 + kt);
            rb1 = *(const uint4*)(B + boff1 + kt);
        }
        bf16x8 af[4], bfr[4];
#pragma unroll
        for (int m = 0; m < 4; ++m) af[m] = *(const bf16x8*)(As + (arow + m * 16) * 40 + kg);
#pragma unroll
        for (int n = 0; n < 4; ++n) bfr[n] = *(const bf16x8*)(Bs + (brow + n * 16) * 40 + kg);
#pragma unroll
        for (int m = 0; m < 4; ++m)
#pragma unroll
            for (int n = 0; n < 4; ++n)
                acc[m][n] = __builtin_amdgcn_mfma_f32_16x16x32_bf16(af[m], bfr[n], acc[m][n], 0, 0, 0);
    }

    const int crow0 = bm * 128 + wr * 64 + (lane >> 4) * 4;
    const int ccol0 = bn * 128 + wc * 64 + (lane & 15);
#pragma unroll
    for (int m = 0; m < 4; ++m)
#pragma unroll
        for (int n = 0; n < 4; ++n)
#pragma unroll
            for (int j = 0; j < 4; ++j) {
                int row = crow0 + m * 16 + j;
                int col = ccol0 + n * 16;
                if constexpr (sizeof(CT) == 2)
                    C[(size_t)row * N + col] = (CT)f2b(acc[m][n][j]);
                else
                    C[(size_t)row * N + col] = (CT)acc[m][n][j];
            }
}

// ---------------------------------------------------------------------------
// conv + silu + surprise stats + beta/amp MLPs -> records (one batch)
// lane owns dims (2*lane, 2*lane+1); record: q~@128 k@256 E@384 v@512 beta@640
// ---------------------------------------------------------------------------
__global__ __launch_bounds__(256) void conv_stats_kernel(
    const ushort* __restrict__ qkv,
    const float* __restrict__ convq, const float* __restrict__ convk,
    const float* __restrict__ convv, const float* __restrict__ Wsv,
    const float* __restrict__ Wb1, const float* __restrict__ bb1,
    const float* __restrict__ Wb2, const float* __restrict__ bb2,
    const float* __restrict__ Wa1, const float* __restrict__ ba1,
    const float* __restrict__ Wa2, const float* __restrict__ ba2,
    const float* __restrict__ A_log, const float* __restrict__ dt_bias,
    ushort* __restrict__ P) {
    __shared__ ushort wsv_s[128 * 136];
    __shared__ float k_sh[4][128];
    for (int i = threadIdx.x; i < 128 * 128; i += 256) {
        int row = i >> 7, col = i & 127;
        wsv_s[row * 136 + col] = f2b(Wsv[i]);
    }
    __syncthreads();
    const int wid = threadIdx.x >> 6, lane = threadIdx.x & 63;

    for (int it = 0; it < 2; ++it) {
        const int pair = blockIdx.x * 8 + it * 4 + wid;   // [0, TB*16)
        const int t = pair >> 4, h = pair & 15;
        const int c0 = h * 128 + 2 * lane, c1 = c0 + 1;

        float wq[4], wq2[4], wk[4], wk2[4], wv[4], wv2[4];
#pragma unroll
        for (int i2 = 0; i2 < 4; ++i2) {
            wq[i2] = convq[c0 * 4 + i2]; wq2[i2] = convq[c1 * 4 + i2];
            wk[i2] = convk[c0 * 4 + i2]; wk2[i2] = convk[c1 * 4 + i2];
            wv[i2] = convv[c0 * 4 + i2]; wv2[i2] = convv[c1 * 4 + i2];
        }
        float aq0 = 0, aq1 = 0, ak0 = 0, ak1 = 0, av0 = 0, av1 = 0;
#pragma unroll
        for (int i2 = 0; i2 < 4; ++i2) {
            int tt = t - 3 + i2;
            if (tt >= 0) {
                const ushort* rowp = qkv + (size_t)tt * 6144 + h * 128;
                uint xq = *(const uint*)(rowp + 2 * lane);
                uint xk = *(const uint*)(rowp + 2048 + 2 * lane);
                uint xv = *(const uint*)(rowp + 4096 + 2 * lane);
                aq0 = fmaf(__uint_as_float(xq << 16), wq[i2], aq0);
                aq1 = fmaf(__uint_as_float(xq & 0xffff0000u), wq2[i2], aq1);
                ak0 = fmaf(__uint_as_float(xk << 16), wk[i2], ak0);
                ak1 = fmaf(__uint_as_float(xk & 0xffff0000u), wk2[i2], ak1);
                av0 = fmaf(__uint_as_float(xv << 16), wv[i2], av0);
                av1 = fmaf(__uint_as_float(xv & 0xffff0000u), wv2[i2], av1);
            }
        }
        float q0 = silu(aq0), q1 = silu(aq1);
        float k0 = silu(ak0), k1 = silu(ak1);
        float v0 = silu(av0), v1 = silu(av1);

        __syncthreads();
        k_sh[wid][2 * lane] = k0;
        k_sh[wid][2 * lane + 1] = k1;
        __syncthreads();

        float vh0 = 0.f, vh1 = 0.f;
        const ushort* wr0 = wsv_s + (2 * lane) * 136;
        const ushort* wr1 = wsv_s + (2 * lane + 1) * 136;
#pragma unroll 4
        for (int j = 0; j < 128; j += 8) {
            float4 ka = *(const float4*)&k_sh[wid][j];
            float4 kb = *(const float4*)&k_sh[wid][j + 4];
            uint4 wa = *(const uint4*)(wr0 + j);
            uint4 wb = *(const uint4*)(wr1 + j);
            vh0 = fmaf(__uint_as_float(wa.x << 16), ka.x, vh0);
            vh0 = fmaf(__uint_as_float(wa.x & 0xffff0000u), ka.y, vh0);
            vh0 = fmaf(__uint_as_float(wa.y << 16), ka.z, vh0);
            vh0 = fmaf(__uint_as_float(wa.y & 0xffff0000u), ka.w, vh0);
            vh0 = fmaf(__uint_as_float(wa.z << 16), kb.x, vh0);
            vh0 = fmaf(__uint_as_float(wa.z & 0xffff0000u), kb.y, vh0);
            vh0 = fmaf(__uint_as_float(wa.w << 16), kb.z, vh0);
            vh0 = fmaf(__uint_as_float(wa.w & 0xffff0000u), kb.w, vh0);
            vh1 = fmaf(__uint_as_float(wb.x << 16), ka.x, vh1);
            vh1 = fmaf(__uint_as_float(wb.x & 0xffff0000u), ka.y, vh1);
            vh1 = fmaf(__uint_as_float(wb.y << 16), ka.z, vh1);
            vh1 = fmaf(__uint_as_float(wb.y & 0xffff0000u), ka.w, vh1);
            vh1 = fmaf(__uint_as_float(wb.z << 16), kb.x, vh1);
            vh1 = fmaf(__uint_as_float(wb.z & 0xffff0000u), kb.y, vh1);
            vh1 = fmaf(__uint_as_float(wb.w << 16), kb.z, vh1);
            vh1 = fmaf(__uint_as_float(wb.w & 0xffff0000u), kb.w, vh1);
        }

        float e0 = vh0 - v0, e1 = vh1 - v1;
        float se2 = e0 * e0 + e1 * e1;
        float sl1 = fabsf(e0) + fabsf(e1);
        float shv = vh0 * v0 + vh1 * v1;
        float shh = vh0 * vh0 + vh1 * vh1;
        float svv = v0 * v0 + v1 * v1;
        float sk2 = k0 * k0 + k1 * k1;
        float sq2 = q0 * q0 + q1 * q1;
#pragma unroll
        for (int m = 32; m >= 1; m >>= 1) {
            se2 += __shfl_xor(se2, m);
            sl1 += __shfl_xor(sl1, m);
            shv += __shfl_xor(shv, m);
            shh += __shfl_xor(shh, m);
            svv += __shfl_xor(svv, m);
            sk2 += __shfl_xor(sk2, m);
            sq2 += __shfl_xor(sq2, m);
        }
        float s_l2 = sqrtf(se2 + 1e-6f);
        float s_l1 = sl1;
        float s_cos = 1.0f - shv / (sqrtf(shh + 1e-6f) * sqrtf(svv + 1e-6f) + 1e-6f);

        const int j2 = lane & 31;
        const float* W1 = (lane < 32) ? Wb1 : Wa1;
        const float* b1 = (lane < 32) ? bb1 : ba1;
        const float* W2 = (lane < 32) ? Wb2 : Wa2;
        float pre = W1[j2 * 3] * s_l2 + W1[j2 * 3 + 1] * s_l1 + W1[j2 * 3 + 2] * s_cos + b1[j2];
        float val = W2[j2] * silu(pre);
#pragma unroll
        for (int m = 16; m >= 1; m >>= 1) val += __shfl_xor(val, m);
        float pre_b = __shfl(val, 0) + bb2[0];
        float pre_a = __shfl(val, 32) + ba2[0];
        float betav = 1.0f / (1.0f + expf(-pre_b));
        float amp = pre_a;

        float knorm = sqrtf(sk2);
        float rinv = amp / fmaxf(knorm, 1e-12f);
        float ah = expf(A_log[h]);
        float gr0 = fmaf(k0, rinv, dt_bias[c0]);
        float gr1 = fmaf(k1, rinv, dt_bias[c1]);
        float sp0 = (gr0 > 20.f) ? gr0 : log1pf(expf(gr0));
        float sp1 = (gr1 > 20.f) ? gr1 : log1pf(expf(gr1));

        ushort* rec = P + (size_t)h * BHSH + (size_t)t * RSH;
        float kinv = rsqrtf(sk2 + 1e-6f);
        float qinv = rsqrtf(sq2 + 1e-6f) * 0.08838834764831845f;  // * DK^-0.5
        *(uint*)(rec + 128 + 2 * lane) = (uint)f2b(q0 * qinv) | ((uint)f2b(q1 * qinv) << 16);
        *(uint*)(rec + 256 + 2 * lane) = (uint)f2b(k0 * kinv) | ((uint)f2b(k1 * kinv) << 16);
        *(uint*)(rec + 384 + 2 * lane) = (uint)f2b(expf(-ah * sp0)) | ((uint)f2b(expf(-ah * sp1)) << 16);
        *(uint*)(rec + 512 + 2 * lane) = (uint)f2b(v0) | ((uint)f2b(v1) << 16);
        if (lane == 0) *(float*)(rec + 640) = betav;
    }
}

// ---------------------------------------------------------------------------
// phase A: one wave per (stream, chunk).  In-place chunk-block construction.
// Writes KW,QW rows; KVT (transposed, lane owns dim-rows 2l,2l+1); vT; W15;
// UM bf16[16][16].
// ---------------------------------------------------------------------------
__global__ __launch_bounds__(256, 1) void phasea_kernel(ushort* __restrict__ P) {
    __shared__ float lA[4][16][16];
    __shared__ float lU[4][16][16];
    __shared__ float lM[4][16][16];
    const int wid = threadIdx.x >> 6, lane = threadIdx.x & 63;
    const int g = blockIdx.x * 4 + wid;
    const int s = g >> 8, n = g & 255;
    ushort* cb = P + (size_t)s * BHSH + (size_t)n * (16 * RSH);
    char* sb = (char*)cb;
    float (*A_)[16] = lA[wid];
    float (*U_)[16] = lU[wid];
    float (*M_)[16] = lM[wid];

    float kf[32], Ef[32], qf[32], bf[16];
    uint vq[16];
#pragma unroll
    for (int i = 0; i < 16; ++i) {
        const ushort* r = cb + i * RSH;
        uint ku = *(const uint*)(r + 256 + 2 * lane);
        uint eu = *(const uint*)(r + 384 + 2 * lane);
        uint qu = *(const uint*)(r + 128 + 2 * lane);
        vq[i] = *(const uint*)(r + 512 + 2 * lane);
        bf[i] = *(const float*)(r + 640);
        kf[2 * i]     = __uint_as_float(ku << 16);
        kf[2 * i + 1] = __uint_as_float(ku & 0xffff0000u);
        Ef[2 * i]     = __uint_as_float(eu << 16);
        Ef[2 * i + 1] = __uint_as_float(eu & 0xffff0000u);
        qf[2 * i]     = __uint_as_float(qu << 16);
        qf[2 * i + 1] = __uint_as_float(qu & 0xffff0000u);
    }

    float R[32];
    float Pc0 = 1.f, Pc1 = 1.f;
#pragma unroll
    for (int i = 0; i < 16; ++i) {
#pragma unroll
        for (int j = 0; j < 16; ++j) if (j < i) {
            R[2 * j] *= Ef[2 * i];
            R[2 * j + 1] *= Ef[2 * i + 1];
        }
        float Tr[16], Ur[16];
#pragma unroll
        for (int j = 0; j < 16; ++j) { Tr[j] = 0.f; Ur[j] = 0.f; }
#pragma unroll
        for (int j = 0; j < 16; ++j) if (j < i) {
            Tr[j] = kf[2 * i] * R[2 * j] + kf[2 * i + 1] * R[2 * j + 1];
            Ur[j] = qf[2 * i] * R[2 * j] + qf[2 * i + 1] * R[2 * j + 1];
        }
        Ur[i] = qf[2 * i] * kf[2 * i] + qf[2 * i + 1] * kf[2 * i + 1];
#pragma unroll
        for (int m = 1; m <= 32; m <<= 1) {
#pragma unroll
            for (int j = 0; j < 16; ++j) if (j <= i) {
                if (j < i) Tr[j] += __shfl_xor(Tr[j], m);
                Ur[j] += __shfl_xor(Ur[j], m);
            }
        }
        if (lane == 0) {
#pragma unroll
            for (int j = 0; j < 16; ++j) if (j < i) A_[i][j] = bf[i] * Tr[j];
#pragma unroll
            for (int j = 0; j < 16; ++j) if (j <= i) U_[i][j] = Ur[j];
        }
        R[2 * i] = kf[2 * i];
        R[2 * i + 1] = kf[2 * i + 1];
        Pc0 *= Ef[2 * i];
        Pc1 *= Ef[2 * i + 1];
        *(uint*)(sb + (size_t)i * 256 + 4 * lane) =
            (uint)f2b(kf[2 * i] * Pc0) | ((uint)f2b(kf[2 * i + 1] * Pc1) << 16);
        *(uint*)(sb + 4096 + (size_t)i * 256 + 4 * lane) =
            (uint)f2b(qf[2 * i] * Pc0) | ((uint)f2b(qf[2 * i + 1] * Pc1) << 16);
    }
    *(uint*)(sb + 16384 + 4 * lane) = (uint)f2b(Pc0) | ((uint)f2b(Pc1) << 16);
    {
        uint lw[8], hw[8];
#pragma unroll
        for (int w = 0; w < 8; ++w) {
            lw[w] = (vq[2 * w] & 0xffffu) | (vq[2 * w + 1] << 16);
            hw[w] = (vq[2 * w] >> 16) | (vq[2 * w + 1] & 0xffff0000u);
        }
        char* vt0 = sb + 12288 + (size_t)(2 * lane) * 32;
        *(uint4*)(vt0)      = (uint4){lw[0], lw[1], lw[2], lw[3]};
        *(uint4*)(vt0 + 16) = (uint4){lw[4], lw[5], lw[6], lw[7]};
        *(uint4*)(vt0 + 32) = (uint4){hw[0], hw[1], hw[2], hw[3]};
        *(uint4*)(vt0 + 48) = (uint4){hw[4], hw[5], hw[6], hw[7]};
    }
    const int mcol = lane & 15;
    float M[16];
#pragma unroll
    for (int i = 0; i < 16; ++i) {
        float acc = (i == mcol) ? bf[i] : 0.f;
#pragma unroll
        for (int j = 0; j < 16; ++j) if (j < i) acc -= A_[i][j] * M[j];
        M[i] = acc;
    }
    if (lane < 16) {
#pragma unroll
        for (int j = 0; j < 16; ++j) M_[j][lane] = M[j];
    }
    // UM = U M' (bf16 [16][16] row-major @16640); lane m = col
    if (lane < 16) {
#pragma unroll
        for (int i = 0; i < 16; ++i) {
            float acc = 0.f;
#pragma unroll
            for (int j = 0; j < 16; ++j) if (j <= i) acc += U_[i][j] * M[j];
            *(ushort*)(sb + 16640 + (size_t)i * 32 + lane * 2) = f2b(acc);
        }
    }
    // KVT[d][m] = sum_{j>=m} M'[j][m] * KU_j[d]  (lane owns dim rows 2l,2l+1)
    {
        float kvA[16], kvB[16];
#pragma unroll
        for (int m = 0; m < 16; ++m) {
            float a0 = 0.f, a1 = 0.f;
#pragma unroll
            for (int j = 0; j < 16; ++j) if (j >= m) {
                float mv = M_[j][m];
                a0 = fmaf(mv, R[2 * j], a0);
                a1 = fmaf(mv, R[2 * j + 1], a1);
            }
            kvA[m] = a0; kvB[m] = a1;
        }
        uint wa[8], wb[8];
#pragma unroll
        for (int w = 0; w < 8; ++w) {
            wa[w] = (uint)f2b(kvA[2 * w]) | ((uint)f2b(kvA[2 * w + 1]) << 16);
            wb[w] = (uint)f2b(kvB[2 * w]) | ((uint)f2b(kvB[2 * w + 1]) << 16);
        }
        char* kt = sb + 8192 + (size_t)(2 * lane) * 32;
        *(uint4*)(kt)      = (uint4){wa[0], wa[1], wa[2], wa[3]};
        *(uint4*)(kt + 16) = (uint4){wa[4], wa[5], wa[6], wa[7]};
        *(uint4*)(kt + 32) = (uint4){wb[0], wb[1], wb[2], wb[3]};
        *(uint4*)(kt + 48) = (uint4){wb[4], wb[5], wb[6], wb[7]};
    }
}

// ---------------------------------------------------------------------------
// phase B (MFMA): one wave per (stream, 16-col group); 64 threads/block.
// S held as 8 f32 16x16 D-tiles; per chunk 25 mfma_16x16x16_bf16.
// ---------------------------------------------------------------------------
struct FragPB { uint2 kw[8], qw[8], kvt[8], w15[8], vv, um; };

__global__ __launch_bounds__(64, 1) void phaseb_kernel(const ushort* __restrict__ P,
                                                       ushort* __restrict__ ob,
                                                       int smask, int sshift) {
    const int l = threadIdx.x;
    const int r16 = l & 15, g4 = l >> 4;
    const int s = blockIdx.x & smask, c = blockIdx.x >> sshift;
    const int b = s >> 4, h = s & 15;
    const int colbase = c * 16;
    const char* gb = (const char*)(P + (size_t)s * BHSH);
    ushort* opb = ob + (size_t)b * (TB * 2048) + h * 128 + colbase + r16;

    const int okw = r16 * 256 + g4 * 8;
    const int okvt = 8192 + r16 * 32 + g4 * 8;
    const int ow15 = 16384 + g4 * 8;
    const int ovv = 12288 + (colbase + r16) * 32 + g4 * 8;
    const int oum = 16640 + r16 * 32 + g4 * 8;

    auto ld = [&](FragPB& F, const char* sb) {
#pragma unroll
        for (int t = 0; t < 8; ++t) {
            F.kw[t]  = *(const uint2*)(sb + okw + t * 32);
            F.qw[t]  = *(const uint2*)(sb + 4096 + okw + t * 32);
            F.kvt[t] = *(const uint2*)(sb + okvt + t * 512);
            F.w15[t] = *(const uint2*)(sb + ow15 + t * 32);
        }
        F.vv = *(const uint2*)(sb + ovv);
        F.um = *(const uint2*)(sb + oum);
    };

    FragPB Fa, Fb;
    ld(Fa, gb);

    floatx4 S[8];
#pragma unroll
    for (int t = 0; t < 8; ++t) S[t] = (floatx4){0.f, 0.f, 0.f, 0.f};

    auto body = [&](int n, FragPB& F, FragPB& FN) {
        // issue next chunk's fragment loads
        int np = n + 1; if (np > 255) np = 255;
        ld(FN, gb + (size_t)np * CSB);
        asm volatile("" ::: "memory");
        // pack S -> bf16 B-frags (B k-layout == D row layout)
        bf16x4 bs[8];
#pragma unroll
        for (int t = 0; t < 8; ++t) {
            bf16x4 v;
            v[0] = (short)f2b(S[t].x); v[1] = (short)f2b(S[t].y);
            v[2] = (short)f2b(S[t].z); v[3] = (short)f2b(S[t].w);
            bs[t] = v;
        }
        floatx4 Y = (floatx4){0.f, 0.f, 0.f, 0.f};
        floatx4 Z = (floatx4){0.f, 0.f, 0.f, 0.f};
#pragma unroll
        for (int t = 0; t < 8; ++t) {
            Y = MFMA16(asbf(F.kw[t]), bs[t], Y);
            Z = MFMA16(asbf(F.qw[t]), bs[t], Z);
        }
        // rr = v - Y  (D-layout rows = time i = g4*4+j)
        float vf[4];
        dec4(F.vv, vf);
        bf16x4 rb;
        rb[0] = (short)f2b(vf[0] - Y.x); rb[1] = (short)f2b(vf[1] - Y.y);
        rb[2] = (short)f2b(vf[2] - Y.z); rb[3] = (short)f2b(vf[3] - Y.w);
        // o = UM @ rr + Z
        floatx4 O = MFMA16(asbf(F.um), rb, Z);
#pragma unroll
        for (int j = 0; j < 4; ++j)
            opb[(size_t)(n * 16 + g4 * 4 + j) * 2048] = f2b(O[j]);
        // S' = diag(W15) S + KVT @ rr
#pragma unroll
        for (int t = 0; t < 8; ++t) {
            float wf[4];
            dec4(F.w15[t], wf);
            floatx4 Cc = (floatx4){wf[0] * S[t].x, wf[1] * S[t].y,
                                   wf[2] * S[t].z, wf[3] * S[t].w};
            S[t] = MFMA16(asbf(F.kvt[t]), rb, Cc);
        }
    };

    for (int n = 0; n < 256; n += 2) {
        body(n, Fa, Fb);
        body(n + 1, Fb, Fa);
    }
}

// ---------------------------------------------------------------------------
// gated RMS norm: og = bf16( o*rsqrt(mean o^2+1e-5)*norm_w*sigmoid(gate+bg2) )
// ---------------------------------------------------------------------------
__global__ __launch_bounds__(256) void normgate_kernel(
    const ushort* __restrict__ o, const ushort* __restrict__ gate,
    const float* __restrict__ bg2, const float* __restrict__ norm_w,
    ushort* __restrict__ og) {
    const int lane = threadIdx.x & 63;
    const int wstart = (blockIdx.x * 256 + threadIdx.x) >> 6;
    const int nw = (gridDim.x * 256) >> 6;
    for (int pair = wstart; pair < TB * 16; pair += nw) {
        const int t = pair >> 4, h = pair & 15;
        const size_t basep = (size_t)t * 2048 + h * 128 + lane * 2;
        unsigned int ovu = *(const unsigned int*)(o + basep);
        float o0 = __uint_as_float(ovu << 16);
        float o1 = __uint_as_float(ovu & 0xffff0000u);
        float ss = o0 * o0 + o1 * o1;
#pragma unroll
        for (int m = 32; m >= 1; m >>= 1) ss += __shfl_xor(ss, m);
        float rn = rsqrtf(ss * (1.0f / 128.0f) + 1e-5f);
        const int dg = h * 128 + lane * 2;
        unsigned int gv = *(const unsigned int*)(gate + basep);
        float g0 = __uint_as_float(gv << 16) + bg2[dg];
        float g1 = __uint_as_float(gv & 0xffff0000u) + bg2[dg + 1];
        float w0 = norm_w[lane * 2], w1 = norm_w[lane * 2 + 1];
        float r0 = o0 * rn * w0 / (1.0f + expf(-g0));
        float r1 = o1 * rn * w1 / (1.0f + expf(-g1));
        unsigned int outw = (unsigned int)f2b(r0) | ((unsigned int)f2b(r1) << 16);
        *(unsigned int*)(og + basep) = outw;
    }
}

// ---------------------------------------------------------------------------
extern "C" void kernel_launch(void* const* d_in, const int* in_sizes, int n_in,
                              void* d_out, int out_size, void* d_ws, size_t ws_size,
                              hipStream_t stream) {
    const float* x = (const float*)d_in[0];
    const float* Wq = (const float*)d_in[1];
    const float* Wk = (const float*)d_in[2];
    const float* Wv = (const float*)d_in[3];
    const float* convq = (const float*)d_in[4];
    const float* convk = (const float*)d_in[5];
    const float* convv = (const float*)d_in[6];
    const float* A_log = (const float*)d_in[7];
    const float* dt_bias = (const float*)d_in[8];
    const float* Wsv = (const float*)d_in[9];
    const float* Wb1 = (const float*)d_in[10];
    const float* bb1 = (const float*)d_in[11];
    const float* Wb2 = (const float*)d_in[12];
    const float* bb2 = (const float*)d_in[13];
    const float* Wa1 = (const float*)d_in[14];
    const float* ba1 = (const float*)d_in[15];
    const float* Wa2 = (const float*)d_in[16];
    const float* ba2 = (const float*)d_in[17];
    const float* Wg1 = (const float*)d_in[18];
    const float* Wg2 = (const float*)d_in[19];
    const float* bg2 = (const float*)d_in[20];
    const float* norm_w = (const float*)d_in[21];
    const float* Wo = (const float*)d_in[22];

    // ---- workspace layout (bytes) ----
    const size_t PBATCH   = (size_t)16 * BHSH * 2;      // 87,031,808 per batch
    const size_t OFF_WQKV = 0;                          // 25,165,824
    const size_t OFF_XB   = OFF_WQKV + 25165824;        // 16,777,216
    const size_t OFF_WG1  = OFF_XB + 16777216;          //    524,288
    const size_t OFF_WG2  = OFF_WG1 + 524288;           //    524,288
    const size_t OFF_QKV  = OFF_WG2 + 524288;           // 50,331,648
    const size_t OFF_P    = OFF_QKV + 50331648;         // = 93,323,264
    const size_t NEED_B   = OFF_P + PBATCH;             // ~180.4 MB
    const size_t NEED_A   = OFF_P + 2 * PBATCH;         // ~267.4 MB
    if (ws_size < NEED_B) return;  // diagnostic guard
    const bool planA = (ws_size >= NEED_A);

    char* ws = (char*)d_ws;
    ushort* wqkv = (ushort*)(ws + OFF_WQKV);
    ushort* xb   = (ushort*)(ws + OFF_XB);
    ushort* wg1b = (ushort*)(ws + OFF_WG1);
    ushort* wg2b = (ushort*)(ws + OFF_WG2);
    ushort* qkvb = (ushort*)(ws + OFF_QKV);
    ushort* P    = (ushort*)(ws + OFF_P);
    ushort* gateb = qkvb;                               // +0        16,777,216
    ushort* xg1b  = (ushort*)(ws + OFF_QKV + 16777216); // +16.78M    1,048,576
    ushort* ogb   = (ushort*)(ws + OFF_QKV + 17825792); // +17.83M   16,777,216
    ushort* wob   = (ushort*)(ws + OFF_QKV + 34603008); // +34.60M    8,388,608
    ushort* obp = planA ? (ushort*)(ws + OFF_WQKV) : xb;

    // weight casts
    cast_f32_bf16<<<512, 256, 0, stream>>>(Wq, wqkv, 4194304);
    cast_f32_bf16<<<512, 256, 0, stream>>>(Wk, wqkv + 4194304, 4194304);
    cast_f32_bf16<<<512, 256, 0, stream>>>(Wv, wqkv + 8388608, 4194304);
    cast_f32_bf16<<<64, 256, 0, stream>>>(Wg1, wg1b, 262144);
    cast_f32_bf16<<<64, 256, 0, stream>>>(Wg2, wg2b, 262144);

    if (planA) {
        for (int b = 0; b < 2; ++b) {
            cast_f32_bf16<<<512, 256, 0, stream>>>(x + (size_t)b * TB * 2048, xb, TB * 2048);
            gemm_bf16<ushort><<<dim3(48, TB / 128), 256, 0, stream>>>(xb, wqkv, qkvb, TB, 6144, 2048);
            conv_stats_kernel<<<TB * 16 / 8, 256, 0, stream>>>(qkvb, convq, convk, convv, Wsv,
                Wb1, bb1, Wb2, bb2, Wa1, ba1, Wa2, ba2, A_log, dt_bias,
                P + (size_t)b * 16 * BHSH);
        }
        phasea_kernel<<<2048, 256, 0, stream>>>(P);
        phaseb_kernel<<<256, 64, 0, stream>>>(P, obp, 31, 5);
        cast_f32_bf16<<<512, 256, 0, stream>>>(Wo, wob, 4194304);
        for (int b = 0; b < 2; ++b) {
            ushort* xstage = ogb;
            cast_f32_bf16<<<512, 256, 0, stream>>>(x + (size_t)b * TB * 2048, xstage, TB * 2048);
            gemm_bf16<ushort><<<dim3(1, TB / 128), 256, 0, stream>>>(xstage, wg1b, xg1b, TB, 128, 2048);
            gemm_bf16<ushort><<<dim3(16, TB / 128), 256, 0, stream>>>(xg1b, wg2b, gateb, TB, 2048, 128);
            normgate_kernel<<<2048, 256, 0, stream>>>(obp + (size_t)b * TB * 2048, gateb, bg2, norm_w, ogb);
            gemm_bf16<float><<<dim3(16, TB / 128), 256, 0, stream>>>(ogb, wob,
                (float*)d_out + (size_t)b * TB * 2048, TB, 2048, 2048);
        }
    } else {
        for (int b = 0; b < 2; ++b) {
            const float* xbp = x + (size_t)b * TB * 2048;
            float* outp = (float*)d_out + (size_t)b * TB * 2048;
            cast_f32_bf16<<<512, 256, 0, stream>>>(xbp, xb, TB * 2048);
            gemm_bf16<ushort><<<dim3(48, TB / 128), 256, 0, stream>>>(xb, wqkv, qkvb, TB, 6144, 2048);
            conv_stats_kernel<<<TB * 16 / 8, 256, 0, stream>>>(qkvb, convq, convk, convv, Wsv,
                Wb1, bb1, Wb2, bb2, Wa1, ba1, Wa2, ba2, A_log, dt_bias, P);
            gemm_bf16<ushort><<<dim3(1, TB / 128), 256, 0, stream>>>(xb, wg1b, xg1b, TB, 128, 2048);
            gemm_bf16<ushort><<<dim3(16, TB / 128), 256, 0, stream>>>(xg1b, wg2b, gateb, TB, 2048, 128);
            cast_f32_bf16<<<512, 256, 0, stream>>>(Wo, wob, 4194304);
            phasea_kernel<<<1024, 256, 0, stream>>>(P);
            phaseb_kernel<<<128, 64, 0, stream>>>(P, xb, 15, 4);   // xb dead -> ob
            normgate_kernel<<<2048, 256, 0, stream>>>(xb, gateb, bg2, norm_w, ogb);
            gemm_bf16<float><<<dim3(16, TB / 128), 256, 0, stream>>>(ogb, wob, outp, TB, 2048, 2048);
        }
    }
}